// Round 1
// baseline (1568.474 us; speedup 1.0000x reference)
//
#include <hip/hip_runtime.h>
#include <hip/hip_bf16.h>
#include <stdint.h>

#define NE 8
#define TKK 2
#define DD 2048
#define FF 4096
#define TT 4096   // tokens = 2*2048

typedef __attribute__((ext_vector_type(8))) short bf16x8;
typedef __attribute__((ext_vector_type(4))) float f32x4;

__device__ inline unsigned short f2bf(float f) {
  union { float f; unsigned u; } x; x.f = f;
  unsigned r = x.u + 0x7fffu + ((x.u >> 16) & 1u);
  return (unsigned short)(r >> 16);
}

#define GLL16(g, l) __builtin_amdgcn_global_load_lds( \
    (__attribute__((address_space(1))) void*)(void*)(g), \
    (__attribute__((address_space(3))) void*)(l), 16, 0, 0)

// ---------------- router: logits + top2 + h->bf16 ----------------
__global__ void router_kernel(const float* __restrict__ h, const float* __restrict__ gw,
                              float* __restrict__ logits, unsigned short* __restrict__ hb,
                              int* __restrict__ counts, int* __restrict__ tok_idx,
                              int* __restrict__ sel_e, int* __restrict__ sel_slot,
                              float* __restrict__ sel_w) {
  int t = blockIdx.x;
  int lane = threadIdx.x;
  const float4* hr = (const float4*)(h + (size_t)t * DD);
  float4 hv[8];
  float acc[NE];
#pragma unroll
  for (int e = 0; e < NE; e++) acc[e] = 0.f;
#pragma unroll
  for (int j = 0; j < 8; j++) hv[j] = hr[j * 64 + lane];
  // fused h -> bf16
  ushort4* hbr = (ushort4*)(hb + (size_t)t * DD);
#pragma unroll
  for (int j = 0; j < 8; j++) {
    ushort4 o;
    o.x = f2bf(hv[j].x); o.y = f2bf(hv[j].y); o.z = f2bf(hv[j].z); o.w = f2bf(hv[j].w);
    hbr[j * 64 + lane] = o;
  }
#pragma unroll
  for (int e = 0; e < NE; e++) {
    const float4* g = (const float4*)(gw + (size_t)e * DD);
    float a = 0.f;
#pragma unroll
    for (int j = 0; j < 8; j++) {
      float4 gv = g[j * 64 + lane];
      a += hv[j].x * gv.x + hv[j].y * gv.y + hv[j].z * gv.z + hv[j].w * gv.w;
    }
    acc[e] = a;
  }
#pragma unroll
  for (int e = 0; e < NE; e++) {
    float v = acc[e];
#pragma unroll
    for (int o = 32; o > 0; o >>= 1) v += __shfl_xor(v, o, 64);
    acc[e] = v;
  }
  if (lane == 0) {
#pragma unroll
    for (int e = 0; e < NE; e++) logits[(size_t)t * NE + e] = acc[e];
    int e1 = 0; float m1 = acc[0];
#pragma unroll
    for (int e = 1; e < NE; e++) if (acc[e] > m1) { m1 = acc[e]; e1 = e; }
    int e2 = -1; float m2 = -3.4e38f;
#pragma unroll
    for (int e = 0; e < NE; e++) if (e != e1 && acc[e] > m2) { m2 = acc[e]; e2 = e; }
    float s = expf(m2 - m1);
    float wa = 1.f / (1.f + s);
    float wb = s * wa;
    int s1 = atomicAdd(&counts[e1], 1);
    tok_idx[e1 * TT + s1] = t;
    int s2 = atomicAdd(&counts[e2], 1);
    tok_idx[e2 * TT + s2] = t;
    sel_e[2 * t] = e1; sel_slot[2 * t] = s1; sel_w[2 * t] = wa;
    sel_e[2 * t + 1] = e2; sel_slot[2 * t + 1] = s2; sel_w[2 * t + 1] = wb;
  }
}

__global__ void offsets_kernel(const int* __restrict__ counts, int* __restrict__ offsets) {
  if (threadIdx.x == 0) {
    int r = 0;
    for (int e = 0; e < NE; e++) { offsets[e] = r; r += counts[e]; }
  }
}

// ---------------- gemm1: gated = silu(X w1^T) * (X w3^T), bf16 out ----------------
// grid: 8192 = x(8 xcd) * m(32) * q(32); p = x+8q -> (n = p&31, e = p>>5)
__global__ __launch_bounds__(256) void gemm1_kernel(
    const float* __restrict__ w1, const float* __restrict__ w3,
    const unsigned short* __restrict__ hb, const int* __restrict__ tok_idx,
    const int* __restrict__ counts, const int* __restrict__ offsets,
    unsigned short* __restrict__ gated) {
  __shared__ __align__(16) char lds[48 * 1024];
  char* Ab = lds;
  char* B1b = lds + 16384;
  char* B3b = lds + 32768;

  int bid = blockIdx.x;
  int x = bid & 7;
  int rest = bid >> 3;
  int m = rest & 31;
  int q = rest >> 5;
  int p = x + 8 * q;
  int n = p & 31;
  int e = p >> 5;
  int cnt = counts[e];
  int row0 = m * 128;
  if (row0 >= cnt) return;
  int offe = offsets[e];
  int tid = threadIdx.x;

  // A gather source addresses (element units), swizzled seg
  long asrc[4];
#pragma unroll
  for (int i = 0; i < 4; i++) {
    int r = i * 32 + (tid >> 3);
    int rr = row0 + r; if (rr >= cnt) rr = cnt - 1;
    int tok = tok_idx[e * TT + rr];
    int seg = (tid & 7) ^ (r & 7);
    asrc[i] = (long)tok * DD + seg * 8;
  }

  const float* w1e = w1 + (size_t)e * FF * DD;
  const float* w3e = w3 + (size_t)e * FF * DD;
  int fbase = n * 128;

  f32x4 acc1[4][4], acc3[4][4];
#pragma unroll
  for (int i = 0; i < 4; i++)
#pragma unroll
    for (int j = 0; j < 4; j++) { acc1[i][j] = (f32x4){0,0,0,0}; acc3[i][j] = (f32x4){0,0,0,0}; }

  int wv = tid >> 6;
  int lane = tid & 63;
  int wr = (wv >> 1) * 64;
  int wc = (wv & 1) * 64;
  int lrow = lane & 15;
  int lk = (lane >> 4) * 8;

  int br = tid >> 2;
  int cg = (tid & 3) * 16;
  int s0 = (tid & 3) * 2;

  for (int k0 = 0; k0 < DD; k0 += 64) {
    if (k0) __syncthreads();
    // A: async gather to LDS (linear dest, source pre-swizzled)
#pragma unroll
    for (int i = 0; i < 4; i++)
      GLL16(hb + asrc[i] + k0, Ab + i * 4096 + tid * 16);
    // B1/B3: fp32 load -> bf16 -> swizzled LDS
#pragma unroll
    for (int it = 0; it < 2; it++) {
      int row = it * 64 + br;
      int p7 = row & 7;
      size_t base = (size_t)(fbase + row) * DD + k0 + cg;
      const float4* s1p = (const float4*)(w1e + base);
      const float4* s3p = (const float4*)(w3e + base);
      float4 a0 = s1p[0], a1 = s1p[1], a2 = s1p[2], a3 = s1p[3];
      union { unsigned short u[8]; uint4 v; } pk0, pk1;
      pk0.u[0]=f2bf(a0.x); pk0.u[1]=f2bf(a0.y); pk0.u[2]=f2bf(a0.z); pk0.u[3]=f2bf(a0.w);
      pk0.u[4]=f2bf(a1.x); pk0.u[5]=f2bf(a1.y); pk0.u[6]=f2bf(a1.z); pk0.u[7]=f2bf(a1.w);
      pk1.u[0]=f2bf(a2.x); pk1.u[1]=f2bf(a2.y); pk1.u[2]=f2bf(a2.z); pk1.u[3]=f2bf(a2.w);
      pk1.u[4]=f2bf(a3.x); pk1.u[5]=f2bf(a3.y); pk1.u[6]=f2bf(a3.z); pk1.u[7]=f2bf(a3.w);
      *(uint4*)(B1b + row * 128 + ((s0 ^ p7) * 16)) = pk0.v;
      *(uint4*)(B1b + row * 128 + (((s0 + 1) ^ p7) * 16)) = pk1.v;
      float4 b0 = s3p[0], b1v = s3p[1], b2 = s3p[2], b3 = s3p[3];
      pk0.u[0]=f2bf(b0.x); pk0.u[1]=f2bf(b0.y); pk0.u[2]=f2bf(b0.z); pk0.u[3]=f2bf(b0.w);
      pk0.u[4]=f2bf(b1v.x); pk0.u[5]=f2bf(b1v.y); pk0.u[6]=f2bf(b1v.z); pk0.u[7]=f2bf(b1v.w);
      pk1.u[0]=f2bf(b2.x); pk1.u[1]=f2bf(b2.y); pk1.u[2]=f2bf(b2.z); pk1.u[3]=f2bf(b2.w);
      pk1.u[4]=f2bf(b3.x); pk1.u[5]=f2bf(b3.y); pk1.u[6]=f2bf(b3.z); pk1.u[7]=f2bf(b3.w);
      *(uint4*)(B3b + row * 128 + ((s0 ^ p7) * 16)) = pk0.v;
      *(uint4*)(B3b + row * 128 + (((s0 + 1) ^ p7) * 16)) = pk1.v;
    }
    __syncthreads();
#pragma unroll
    for (int kk = 0; kk < 2; kk++) {
      int kseg = (kk * 32 + lk) >> 3;
      bf16x8 af[4], b1f[4], b3f[4];
#pragma unroll
      for (int i = 0; i < 4; i++) {
        int row = wr + i * 16 + lrow;
        af[i] = *(const bf16x8*)(Ab + row * 128 + ((kseg ^ (row & 7)) * 16));
      }
#pragma unroll
      for (int j = 0; j < 4; j++) {
        int row = wc + j * 16 + lrow;
        int off = row * 128 + ((kseg ^ (row & 7)) * 16);
        b1f[j] = *(const bf16x8*)(B1b + off);
        b3f[j] = *(const bf16x8*)(B3b + off);
      }
#pragma unroll
      for (int i = 0; i < 4; i++)
#pragma unroll
        for (int j = 0; j < 4; j++) {
          acc1[i][j] = __builtin_amdgcn_mfma_f32_16x16x32_bf16(af[i], b1f[j], acc1[i][j], 0, 0, 0);
          acc3[i][j] = __builtin_amdgcn_mfma_f32_16x16x32_bf16(af[i], b3f[j], acc3[i][j], 0, 0, 0);
        }
    }
  }
  // epilogue: silu(c1)*c3 -> bf16
  int crow0 = wr + (lane >> 4) * 4;
  int ccol0 = wc + (lane & 15);
#pragma unroll
  for (int i = 0; i < 4; i++)
#pragma unroll
    for (int j = 0; j < 4; j++)
#pragma unroll
      for (int r = 0; r < 4; r++) {
        int trow = crow0 + i * 16 + r;
        if (row0 + trow < cnt) {
          float g = acc1[i][j][r];
          float sg = g / (1.f + __expf(-g));
          float val = sg * acc3[i][j][r];
          gated[(size_t)(offe + row0 + trow) * FF + (fbase + ccol0 + j * 16)] = f2bf(val);
        }
      }
}

// ---------------- gemm2: eout = gated w2^T (fp32 out) ----------------
// grid: 4096 = x(8) * m(32) * q(16); p = x+8q -> (n = p&15, e = p>>4)
__global__ __launch_bounds__(256) void gemm2_kernel(
    const float* __restrict__ w2, const unsigned short* __restrict__ gated,
    const int* __restrict__ counts, const int* __restrict__ offsets,
    float* __restrict__ eout) {
  __shared__ __align__(16) char lds[32 * 1024];
  char* Ab = lds;
  char* Bb = lds + 16384;

  int bid = blockIdx.x;
  int x = bid & 7;
  int rest = bid >> 3;
  int m = rest & 31;
  int q = rest >> 5;
  int p = x + 8 * q;
  int n = p & 15;
  int e = p >> 4;
  int cnt = counts[e];
  int row0 = m * 128;
  if (row0 >= cnt) return;
  int offe = offsets[e];
  int tid = threadIdx.x;

  long asrc[4];
#pragma unroll
  for (int i = 0; i < 4; i++) {
    int r = i * 32 + (tid >> 3);
    int rr = row0 + r; if (rr >= cnt) rr = cnt - 1;
    int seg = (tid & 7) ^ (r & 7);
    asrc[i] = (long)(offe + rr) * FF + seg * 8;
  }
  const float* w2e = w2 + (size_t)e * DD * FF;
  int dbase = n * 128;

  f32x4 acc[4][4];
#pragma unroll
  for (int i = 0; i < 4; i++)
#pragma unroll
    for (int j = 0; j < 4; j++) acc[i][j] = (f32x4){0,0,0,0};

  int wv = tid >> 6;
  int lane = tid & 63;
  int wr = (wv >> 1) * 64;
  int wc = (wv & 1) * 64;
  int lrow = lane & 15;
  int lk = (lane >> 4) * 8;
  int br = tid >> 2;
  int cg = (tid & 3) * 16;
  int s0 = (tid & 3) * 2;

  for (int k0 = 0; k0 < FF; k0 += 64) {
    if (k0) __syncthreads();
#pragma unroll
    for (int i = 0; i < 4; i++)
      GLL16(gated + asrc[i] + k0, Ab + i * 4096 + tid * 16);
#pragma unroll
    for (int it = 0; it < 2; it++) {
      int row = it * 64 + br;
      int p7 = row & 7;
      const float4* sp = (const float4*)(w2e + (size_t)(dbase + row) * FF + k0 + cg);
      float4 a0 = sp[0], a1 = sp[1], a2 = sp[2], a3 = sp[3];
      union { unsigned short u[8]; uint4 v; } pk0, pk1;
      pk0.u[0]=f2bf(a0.x); pk0.u[1]=f2bf(a0.y); pk0.u[2]=f2bf(a0.z); pk0.u[3]=f2bf(a0.w);
      pk0.u[4]=f2bf(a1.x); pk0.u[5]=f2bf(a1.y); pk0.u[6]=f2bf(a1.z); pk0.u[7]=f2bf(a1.w);
      pk1.u[0]=f2bf(a2.x); pk1.u[1]=f2bf(a2.y); pk1.u[2]=f2bf(a2.z); pk1.u[3]=f2bf(a2.w);
      pk1.u[4]=f2bf(a3.x); pk1.u[5]=f2bf(a3.y); pk1.u[6]=f2bf(a3.z); pk1.u[7]=f2bf(a3.w);
      *(uint4*)(Bb + row * 128 + ((s0 ^ p7) * 16)) = pk0.v;
      *(uint4*)(Bb + row * 128 + (((s0 + 1) ^ p7) * 16)) = pk1.v;
    }
    __syncthreads();
#pragma unroll
    for (int kk = 0; kk < 2; kk++) {
      int kseg = (kk * 32 + lk) >> 3;
      bf16x8 af[4], bf[4];
#pragma unroll
      for (int i = 0; i < 4; i++) {
        int row = wr + i * 16 + lrow;
        af[i] = *(const bf16x8*)(Ab + row * 128 + ((kseg ^ (row & 7)) * 16));
      }
#pragma unroll
      for (int j = 0; j < 4; j++) {
        int row = wc + j * 16 + lrow;
        bf[j] = *(const bf16x8*)(Bb + row * 128 + ((kseg ^ (row & 7)) * 16));
      }
#pragma unroll
      for (int i = 0; i < 4; i++)
#pragma unroll
        for (int j = 0; j < 4; j++)
          acc[i][j] = __builtin_amdgcn_mfma_f32_16x16x32_bf16(af[i], bf[j], acc[i][j], 0, 0, 0);
    }
  }
  int crow0 = wr + (lane >> 4) * 4;
  int ccol0 = wc + (lane & 15);
#pragma unroll
  for (int i = 0; i < 4; i++)
#pragma unroll
    for (int j = 0; j < 4; j++)
#pragma unroll
      for (int r = 0; r < 4; r++) {
        int trow = crow0 + i * 16 + r;
        if (row0 + trow < cnt)
          eout[(size_t)(offe + row0 + trow) * DD + (dbase + ccol0 + j * 16)] = acc[i][j][r];
      }
}

// ---------------- gather: final = sum_k w_k * eout[slot_k] ----------------
__global__ void gather_kernel(const float* __restrict__ eout, const int* __restrict__ offsets,
                              const int* __restrict__ sel_e, const int* __restrict__ sel_slot,
                              const float* __restrict__ sel_w, float* __restrict__ out) {
  int idx = blockIdx.x * 256 + threadIdx.x;
  int t = idx >> 9;          // DD/4 = 512 float4 per row
  int c = idx & 511;
  int ea = sel_e[2 * t], eb = sel_e[2 * t + 1];
  int sa = offsets[ea] + sel_slot[2 * t];
  int sb = offsets[eb] + sel_slot[2 * t + 1];
  float wa = sel_w[2 * t], wb = sel_w[2 * t + 1];
  float4 va = ((const float4*)(eout + (size_t)sa * DD))[c];
  float4 vb = ((const float4*)(eout + (size_t)sb * DD))[c];
  float4 o;
  o.x = wa * va.x + wb * vb.x;
  o.y = wa * va.y + wb * vb.y;
  o.z = wa * va.z + wb * vb.z;
  o.w = wa * va.w + wb * vb.w;
  ((float4*)(out + (size_t)t * DD))[c] = o;
}

extern "C" void kernel_launch(void* const* d_in, const int* in_sizes, int n_in,
                              void* d_out, int out_size, void* d_ws, size_t ws_size,
                              hipStream_t stream) {
  const float* h  = (const float*)d_in[0];
  const float* gw = (const float*)d_in[1];
  const float* w1 = (const float*)d_in[2];
  const float* w2 = (const float*)d_in[3];
  const float* w3 = (const float*)d_in[4];
  float* out = (float*)d_out;
  float* logits = out + (size_t)TT * DD;

  char* wp = (char*)d_ws;
  int* counts = (int*)wp; wp += 256;
  int* offsets = (int*)wp; wp += 256;
  int* tok_idx = (int*)wp; wp += (size_t)NE * TT * 4;
  int* sel_e = (int*)wp; wp += (size_t)TT * 2 * 4;
  int* sel_slot = (int*)wp; wp += (size_t)TT * 2 * 4;
  float* sel_w = (float*)wp; wp += (size_t)TT * 2 * 4;
  unsigned short* hb = (unsigned short*)wp; wp += (size_t)TT * DD * 2;
  unsigned short* gated = (unsigned short*)wp; wp += (size_t)TT * TKK * FF * 2;
  float* eout = (float*)wp; wp += (size_t)TT * TKK * DD * 4;
  if ((size_t)(wp - (char*)d_ws) > ws_size) return;  // ws too small -> visible validation failure

  hipMemsetAsync(counts, 0, 32, stream);
  router_kernel<<<TT, 64, 0, stream>>>(h, gw, logits, hb, counts, tok_idx, sel_e, sel_slot, sel_w);
  offsets_kernel<<<1, 64, 0, stream>>>(counts, offsets);
  gemm1_kernel<<<8 * 32 * 32, 256, 0, stream>>>(w1, w3, hb, tok_idx, counts, offsets, gated);
  gemm2_kernel<<<8 * 32 * 16, 256, 0, stream>>>(w2, gated, counts, offsets, eout);
  gather_kernel<<<(TT * DD / 4) / 256, 256, 0, stream>>>(eout, offsets, sel_e, sel_slot, sel_w, out);
}

// Round 2
// 1062.172 us; speedup vs baseline: 1.4767x; 1.4767x over previous
//
#include <hip/hip_runtime.h>
#include <hip/hip_bf16.h>
#include <stdint.h>

#define NE 8
#define TKK 2
#define DD 2048
#define FF 4096
#define TT 4096   // tokens = 2*2048

typedef __attribute__((ext_vector_type(8))) short bf16x8;
typedef __attribute__((ext_vector_type(4))) float f32x4;

__device__ inline unsigned short f2bf(float f) {
  union { float f; unsigned u; } x; x.f = f;
  unsigned r = x.u + 0x7fffu + ((x.u >> 16) & 1u);
  return (unsigned short)(r >> 16);
}

// 8 floats -> bf16x8 (RNE; compiler may fuse pairs into v_cvt_pk_bf16_f32)
__device__ inline bf16x8 cvt8(float4 a, float4 b) {
  union { unsigned short h[8]; bf16x8 v; } x;
  x.h[0] = f2bf(a.x); x.h[1] = f2bf(a.y); x.h[2] = f2bf(a.z); x.h[3] = f2bf(a.w);
  x.h[4] = f2bf(b.x); x.h[5] = f2bf(b.y); x.h[6] = f2bf(b.z); x.h[7] = f2bf(b.w);
  return x.v;
}

#define GLL16(g, l) __builtin_amdgcn_global_load_lds( \
    (__attribute__((address_space(1))) void*)(void*)(g), \
    (__attribute__((address_space(3))) void*)(l), 16, 0, 0)

// ---------------- router: logits + top2 + h->bf16 ----------------
__global__ void router_kernel(const float* __restrict__ h, const float* __restrict__ gw,
                              float* __restrict__ logits, unsigned short* __restrict__ hb,
                              int* __restrict__ counts, int* __restrict__ tok_idx,
                              int* __restrict__ sel_e, int* __restrict__ sel_slot,
                              float* __restrict__ sel_w) {
  int t = blockIdx.x;
  int lane = threadIdx.x;
  const float4* hr = (const float4*)(h + (size_t)t * DD);
  float4 hv[8];
  float acc[NE];
#pragma unroll
  for (int e = 0; e < NE; e++) acc[e] = 0.f;
#pragma unroll
  for (int j = 0; j < 8; j++) hv[j] = hr[j * 64 + lane];
  ushort4* hbr = (ushort4*)(hb + (size_t)t * DD);
#pragma unroll
  for (int j = 0; j < 8; j++) {
    ushort4 o;
    o.x = f2bf(hv[j].x); o.y = f2bf(hv[j].y); o.z = f2bf(hv[j].z); o.w = f2bf(hv[j].w);
    hbr[j * 64 + lane] = o;
  }
#pragma unroll
  for (int e = 0; e < NE; e++) {
    const float4* g = (const float4*)(gw + (size_t)e * DD);
    float a = 0.f;
#pragma unroll
    for (int j = 0; j < 8; j++) {
      float4 gv = g[j * 64 + lane];
      a += hv[j].x * gv.x + hv[j].y * gv.y + hv[j].z * gv.z + hv[j].w * gv.w;
    }
    acc[e] = a;
  }
#pragma unroll
  for (int e = 0; e < NE; e++) {
    float v = acc[e];
#pragma unroll
    for (int o = 32; o > 0; o >>= 1) v += __shfl_xor(v, o, 64);
    acc[e] = v;
  }
  if (lane == 0) {
#pragma unroll
    for (int e = 0; e < NE; e++) logits[(size_t)t * NE + e] = acc[e];
    int e1 = 0; float m1 = acc[0];
#pragma unroll
    for (int e = 1; e < NE; e++) if (acc[e] > m1) { m1 = acc[e]; e1 = e; }
    int e2 = -1; float m2 = -3.4e38f;
#pragma unroll
    for (int e = 0; e < NE; e++) if (e != e1 && acc[e] > m2) { m2 = acc[e]; e2 = e; }
    float s = expf(m2 - m1);
    float wa = 1.f / (1.f + s);
    float wb = s * wa;
    int s1 = atomicAdd(&counts[e1], 1);
    tok_idx[e1 * TT + s1] = t;
    int s2 = atomicAdd(&counts[e2], 1);
    tok_idx[e2 * TT + s2] = t;
    sel_e[2 * t] = e1; sel_slot[2 * t] = s1; sel_w[2 * t] = wa;
    sel_e[2 * t + 1] = e2; sel_slot[2 * t + 1] = s2; sel_w[2 * t + 1] = wb;
  }
}

__global__ void offsets_kernel(const int* __restrict__ counts, int* __restrict__ offsets) {
  if (threadIdx.x == 0) {
    int r = 0;
    for (int e = 0; e < NE; e++) { offsets[e] = r; r += counts[e]; }
  }
}

// ---------------- gemm1: gated = silu(X w1^T) * (X w3^T), bf16 out ----------------
// Tile 128(M) x 64(F), BK=64. A bf16 via GLL, B1/B3 fp32 via GLL (cvt after ds_read).
// grid: 16384 = x(8) * m(32) * q(64); p = x+8q -> (n = p&63, e = p>>6)
__global__ __launch_bounds__(256) void gemm1_kernel(
    const float* __restrict__ w1, const float* __restrict__ w3,
    const unsigned short* __restrict__ hb, const int* __restrict__ tok_idx,
    const int* __restrict__ counts, const int* __restrict__ offsets,
    unsigned short* __restrict__ gated) {
  __shared__ __align__(16) char lds[48 * 1024];
  char* Ab = lds;              // 128 rows x 128B (bf16)
  char* B1b = lds + 16384;     // 64 rows x 256B (fp32)
  char* B3b = lds + 32768;     // 64 rows x 256B (fp32)

  int bid = blockIdx.x;
  int x = bid & 7;
  int rest = bid >> 3;
  int m = rest & 31;
  int q = rest >> 5;           // 0..63
  int p = x + 8 * q;           // 0..511
  int n = p & 63;
  int e = p >> 6;
  int cnt = counts[e];
  int row0 = m * 128;
  if (row0 >= cnt) return;
  int offe = offsets[e];
  int tid = threadIdx.x;

  // A gather sources (bf16 elements), pre-swizzled seg (8 segs of 8 elems per 128B row)
  long asrc[4];
#pragma unroll
  for (int i = 0; i < 4; i++) {
    int r = i * 32 + (tid >> 3);
    int rr = row0 + r; if (rr >= cnt) rr = cnt - 1;
    int tok = tok_idx[e * TT + rr];
    asrc[i] = (long)tok * DD + (((tid & 7) ^ (r & 7)) * 8);
  }
  // B sources (fp32 elements), 16 segs of 4 floats per 256B row
  int fbase = n * 64;
  long bsrc[4];
#pragma unroll
  for (int i = 0; i < 4; i++) {
    int r = i * 16 + (tid >> 4);
    bsrc[i] = (long)(fbase + r) * DD + (((tid & 15) ^ (r & 15)) * 4);
  }
  const float* w1e = w1 + (size_t)e * FF * DD;
  const float* w3e = w3 + (size_t)e * FF * DD;

  f32x4 acc1[4][2], acc3[4][2];
#pragma unroll
  for (int i = 0; i < 4; i++)
#pragma unroll
    for (int j = 0; j < 2; j++) { acc1[i][j] = (f32x4){0,0,0,0}; acc3[i][j] = (f32x4){0,0,0,0}; }

  int wv = tid >> 6;
  int lane = tid & 63;
  int wr = (wv >> 1) * 64;     // M offset of wave (2x2 waves)
  int wc = (wv & 1) * 32;      // N offset of wave
  int lrow = lane & 15;
  int lk4 = lane >> 4;         // 0..3

  for (int k0 = 0; k0 < DD; k0 += 64) {
    if (k0) __syncthreads();
#pragma unroll
    for (int i = 0; i < 4; i++)
      GLL16(hb + asrc[i] + k0, Ab + i * 4096 + tid * 16);
#pragma unroll
    for (int i = 0; i < 4; i++)
      GLL16(w1e + bsrc[i] + k0, B1b + i * 4096 + tid * 16);
#pragma unroll
    for (int i = 0; i < 4; i++)
      GLL16(w3e + bsrc[i] + k0, B3b + i * 4096 + tid * 16);
    __syncthreads();
#pragma unroll
    for (int kk = 0; kk < 2; kk++) {
      int kseg = kk * 4 + lk4;          // A: 8 segs of 8 bf16
      int fs = kk * 8 + lk4 * 2;        // B: 16 segs of 4 floats
      bf16x8 af[4], b1f[2], b3f[2];
#pragma unroll
      for (int i = 0; i < 4; i++) {
        int row = wr + i * 16 + lrow;
        af[i] = *(const bf16x8*)(Ab + row * 128 + ((kseg ^ (row & 7)) * 16));
      }
#pragma unroll
      for (int j = 0; j < 2; j++) {
        int row = wc + j * 16 + lrow;
        int rx = row & 15;
        float4 a0 = *(const float4*)(B1b + row * 256 + ((fs ^ rx) * 16));
        float4 a1 = *(const float4*)(B1b + row * 256 + (((fs + 1) ^ rx) * 16));
        b1f[j] = cvt8(a0, a1);
        float4 c0 = *(const float4*)(B3b + row * 256 + ((fs ^ rx) * 16));
        float4 c1 = *(const float4*)(B3b + row * 256 + (((fs + 1) ^ rx) * 16));
        b3f[j] = cvt8(c0, c1);
      }
#pragma unroll
      for (int i = 0; i < 4; i++)
#pragma unroll
        for (int j = 0; j < 2; j++) {
          acc1[i][j] = __builtin_amdgcn_mfma_f32_16x16x32_bf16(af[i], b1f[j], acc1[i][j], 0, 0, 0);
          acc3[i][j] = __builtin_amdgcn_mfma_f32_16x16x32_bf16(af[i], b3f[j], acc3[i][j], 0, 0, 0);
        }
    }
  }
  // epilogue: silu(c1)*c3 -> bf16
  int crow0 = wr + (lane >> 4) * 4;
  int ccol0 = wc + (lane & 15);
#pragma unroll
  for (int i = 0; i < 4; i++)
#pragma unroll
    for (int j = 0; j < 2; j++)
#pragma unroll
      for (int r = 0; r < 4; r++) {
        int trow = crow0 + i * 16 + r;
        if (row0 + trow < cnt) {
          float g = acc1[i][j][r];
          float sg = g / (1.f + __expf(-g));
          float val = sg * acc3[i][j][r];
          gated[(size_t)(offe + row0 + trow) * FF + (fbase + ccol0 + j * 16)] = f2bf(val);
        }
      }
}

// ---------------- gemm2: eout = gated w2^T (fp32 out) ----------------
// Tile 128(M) x 128(D), BK=64, K=FF. A bf16 via GLL, B fp32 via GLL.
// grid: 4096 = x(8) * m(32) * q(16); p = x+8q -> (n = p&15, e = p>>4)
__global__ __launch_bounds__(256) void gemm2_kernel(
    const float* __restrict__ w2, const unsigned short* __restrict__ gated,
    const int* __restrict__ counts, const int* __restrict__ offsets,
    float* __restrict__ eout) {
  __shared__ __align__(16) char lds[48 * 1024];
  char* Ab = lds;              // 128 rows x 128B (bf16)
  char* Bb = lds + 16384;      // 128 rows x 256B (fp32)

  int bid = blockIdx.x;
  int x = bid & 7;
  int rest = bid >> 3;
  int m = rest & 31;
  int q = rest >> 5;           // 0..15
  int p = x + 8 * q;           // 0..127
  int n = p & 15;
  int e = p >> 4;
  int cnt = counts[e];
  int row0 = m * 128;
  if (row0 >= cnt) return;
  int offe = offsets[e];
  int tid = threadIdx.x;

  long asrc[4];
#pragma unroll
  for (int i = 0; i < 4; i++) {
    int r = i * 32 + (tid >> 3);
    int rr = row0 + r; if (rr >= cnt) rr = cnt - 1;
    asrc[i] = (long)(offe + rr) * FF + (((tid & 7) ^ (r & 7)) * 8);
  }
  int dbase = n * 128;
  long bsrc[8];
#pragma unroll
  for (int i = 0; i < 8; i++) {
    int r = i * 16 + (tid >> 4);
    bsrc[i] = (long)(dbase + r) * FF + (((tid & 15) ^ (r & 15)) * 4);
  }
  const float* w2e = w2 + (size_t)e * DD * FF;

  f32x4 acc[4][4];
#pragma unroll
  for (int i = 0; i < 4; i++)
#pragma unroll
    for (int j = 0; j < 4; j++) acc[i][j] = (f32x4){0,0,0,0};

  int wv = tid >> 6;
  int lane = tid & 63;
  int wr = (wv >> 1) * 64;
  int wc = (wv & 1) * 64;
  int lrow = lane & 15;
  int lk4 = lane >> 4;

  for (int k0 = 0; k0 < FF; k0 += 64) {
    if (k0) __syncthreads();
#pragma unroll
    for (int i = 0; i < 4; i++)
      GLL16(gated + asrc[i] + k0, Ab + i * 4096 + tid * 16);
#pragma unroll
    for (int i = 0; i < 8; i++)
      GLL16(w2e + bsrc[i] + k0, Bb + i * 4096 + tid * 16);
    __syncthreads();
#pragma unroll
    for (int kk = 0; kk < 2; kk++) {
      int kseg = kk * 4 + lk4;
      int fs = kk * 8 + lk4 * 2;
      bf16x8 af[4], bf[4];
#pragma unroll
      for (int i = 0; i < 4; i++) {
        int row = wr + i * 16 + lrow;
        af[i] = *(const bf16x8*)(Ab + row * 128 + ((kseg ^ (row & 7)) * 16));
      }
#pragma unroll
      for (int j = 0; j < 4; j++) {
        int row = wc + j * 16 + lrow;
        int rx = row & 15;
        float4 a0 = *(const float4*)(Bb + row * 256 + ((fs ^ rx) * 16));
        float4 a1 = *(const float4*)(Bb + row * 256 + (((fs + 1) ^ rx) * 16));
        bf[j] = cvt8(a0, a1);
      }
#pragma unroll
      for (int i = 0; i < 4; i++)
#pragma unroll
        for (int j = 0; j < 4; j++)
          acc[i][j] = __builtin_amdgcn_mfma_f32_16x16x32_bf16(af[i], bf[j], acc[i][j], 0, 0, 0);
    }
  }
  int crow0 = wr + (lane >> 4) * 4;
  int ccol0 = wc + (lane & 15);
#pragma unroll
  for (int i = 0; i < 4; i++)
#pragma unroll
    for (int j = 0; j < 4; j++)
#pragma unroll
      for (int r = 0; r < 4; r++) {
        int trow = crow0 + i * 16 + r;
        if (row0 + trow < cnt)
          eout[(size_t)(offe + row0 + trow) * DD + (dbase + ccol0 + j * 16)] = acc[i][j][r];
      }
}

// ---------------- gather: final = sum_k w_k * eout[slot_k] ----------------
__global__ void gather_kernel(const float* __restrict__ eout, const int* __restrict__ offsets,
                              const int* __restrict__ sel_e, const int* __restrict__ sel_slot,
                              const float* __restrict__ sel_w, float* __restrict__ out) {
  int idx = blockIdx.x * 256 + threadIdx.x;
  int t = idx >> 9;          // DD/4 = 512 float4 per row
  int c = idx & 511;
  int ea = sel_e[2 * t], eb = sel_e[2 * t + 1];
  int sa = offsets[ea] + sel_slot[2 * t];
  int sb = offsets[eb] + sel_slot[2 * t + 1];
  float wa = sel_w[2 * t], wb = sel_w[2 * t + 1];
  float4 va = ((const float4*)(eout + (size_t)sa * DD))[c];
  float4 vb = ((const float4*)(eout + (size_t)sb * DD))[c];
  float4 o;
  o.x = wa * va.x + wb * vb.x;
  o.y = wa * va.y + wb * vb.y;
  o.z = wa * va.z + wb * vb.z;
  o.w = wa * va.w + wb * vb.w;
  ((float4*)(out + (size_t)t * DD))[c] = o;
}

extern "C" void kernel_launch(void* const* d_in, const int* in_sizes, int n_in,
                              void* d_out, int out_size, void* d_ws, size_t ws_size,
                              hipStream_t stream) {
  const float* h  = (const float*)d_in[0];
  const float* gw = (const float*)d_in[1];
  const float* w1 = (const float*)d_in[2];
  const float* w2 = (const float*)d_in[3];
  const float* w3 = (const float*)d_in[4];
  float* out = (float*)d_out;
  float* logits = out + (size_t)TT * DD;

  char* wp = (char*)d_ws;
  int* counts = (int*)wp; wp += 256;
  int* offsets = (int*)wp; wp += 256;
  int* tok_idx = (int*)wp; wp += (size_t)NE * TT * 4;
  int* sel_e = (int*)wp; wp += (size_t)TT * 2 * 4;
  int* sel_slot = (int*)wp; wp += (size_t)TT * 2 * 4;
  float* sel_w = (float*)wp; wp += (size_t)TT * 2 * 4;
  unsigned short* hb = (unsigned short*)wp; wp += (size_t)TT * DD * 2;
  unsigned short* gated = (unsigned short*)wp; wp += (size_t)TT * TKK * FF * 2;
  float* eout = (float*)wp; wp += (size_t)TT * TKK * DD * 4;
  if ((size_t)(wp - (char*)d_ws) > ws_size) return;  // ws too small -> visible validation failure

  hipMemsetAsync(counts, 0, 32, stream);
  router_kernel<<<TT, 64, 0, stream>>>(h, gw, logits, hb, counts, tok_idx, sel_e, sel_slot, sel_w);
  offsets_kernel<<<1, 64, 0, stream>>>(counts, offsets);
  gemm1_kernel<<<8 * 32 * 64, 256, 0, stream>>>(w1, w3, hb, tok_idx, counts, offsets, gated);
  gemm2_kernel<<<8 * 32 * 16, 256, 0, stream>>>(w2, gated, counts, offsets, eout);
  gather_kernel<<<(TT * DD / 4) / 256, 256, 0, stream>>>(eout, offsets, sel_e, sel_slot, sel_w, out);
}

// Round 4
// 860.586 us; speedup vs baseline: 1.8226x; 1.2342x over previous
//
#include <hip/hip_runtime.h>
#include <hip/hip_bf16.h>
#include <stdint.h>

#define NE 8
#define TKK 2
#define DD 2048
#define FF 4096
#define TT 4096   // tokens = 2*2048

typedef __attribute__((ext_vector_type(8))) short bf16x8;
typedef __attribute__((ext_vector_type(4))) float f32x4;

__device__ inline unsigned short f2bf(float f) {
  union { float f; unsigned u; } x; x.f = f;
  unsigned r = x.u + 0x7fffu + ((x.u >> 16) & 1u);
  return (unsigned short)(r >> 16);
}

__device__ inline bf16x8 cvt8(float4 a, float4 b) {
  union { unsigned short h[8]; bf16x8 v; } x;
  x.h[0] = f2bf(a.x); x.h[1] = f2bf(a.y); x.h[2] = f2bf(a.z); x.h[3] = f2bf(a.w);
  x.h[4] = f2bf(b.x); x.h[5] = f2bf(b.y); x.h[6] = f2bf(b.z); x.h[7] = f2bf(b.w);
  return x.v;
}

#define GLL16(g, l) __builtin_amdgcn_global_load_lds( \
    (__attribute__((address_space(1))) void*)(void*)(g), \
    (__attribute__((address_space(3))) void*)(l), 16, 0, 0)

// ---------------- weight fp32 -> bf16 streaming convert ----------------
__global__ void convert_kernel(const float* __restrict__ src, unsigned short* __restrict__ dst, long n) {
  long i = ((long)blockIdx.x * 256 + threadIdx.x) * 8;
  long stride = (long)gridDim.x * 256 * 8;
  for (; i < n; i += stride) {
    float4 a = *(const float4*)(src + i);
    float4 b = *(const float4*)(src + i + 4);
    union { unsigned short h[8]; uint4 v; } o;
    o.h[0] = f2bf(a.x); o.h[1] = f2bf(a.y); o.h[2] = f2bf(a.z); o.h[3] = f2bf(a.w);
    o.h[4] = f2bf(b.x); o.h[5] = f2bf(b.y); o.h[6] = f2bf(b.z); o.h[7] = f2bf(b.w);
    *(uint4*)(dst + i) = o.v;
  }
}

// ---------------- router: logits + top2 + h->bf16 ----------------
__global__ void router_kernel(const float* __restrict__ h, const float* __restrict__ gw,
                              float* __restrict__ logits, unsigned short* __restrict__ hb,
                              int* __restrict__ counts, int* __restrict__ tok_idx,
                              int* __restrict__ sel_e, int* __restrict__ sel_slot,
                              float* __restrict__ sel_w) {
  int t = blockIdx.x;
  int lane = threadIdx.x;
  const float4* hr = (const float4*)(h + (size_t)t * DD);
  float4 hv[8];
  float acc[NE];
#pragma unroll
  for (int e = 0; e < NE; e++) acc[e] = 0.f;
#pragma unroll
  for (int j = 0; j < 8; j++) hv[j] = hr[j * 64 + lane];
  ushort4* hbr = (ushort4*)(hb + (size_t)t * DD);
#pragma unroll
  for (int j = 0; j < 8; j++) {
    ushort4 o;
    o.x = f2bf(hv[j].x); o.y = f2bf(hv[j].y); o.z = f2bf(hv[j].z); o.w = f2bf(hv[j].w);
    hbr[j * 64 + lane] = o;
  }
#pragma unroll
  for (int e = 0; e < NE; e++) {
    const float4* g = (const float4*)(gw + (size_t)e * DD);
    float a = 0.f;
#pragma unroll
    for (int j = 0; j < 8; j++) {
      float4 gv = g[j * 64 + lane];
      a += hv[j].x * gv.x + hv[j].y * gv.y + hv[j].z * gv.z + hv[j].w * gv.w;
    }
    acc[e] = a;
  }
#pragma unroll
  for (int e = 0; e < NE; e++) {
    float v = acc[e];
#pragma unroll
    for (int o = 32; o > 0; o >>= 1) v += __shfl_xor(v, o, 64);
    acc[e] = v;
  }
  if (lane == 0) {
#pragma unroll
    for (int e = 0; e < NE; e++) logits[(size_t)t * NE + e] = acc[e];
    int e1 = 0; float m1 = acc[0];
#pragma unroll
    for (int e = 1; e < NE; e++) if (acc[e] > m1) { m1 = acc[e]; e1 = e; }
    int e2 = -1; float m2 = -3.4e38f;
#pragma unroll
    for (int e = 0; e < NE; e++) if (e != e1 && acc[e] > m2) { m2 = acc[e]; e2 = e; }
    float s = expf(m2 - m1);
    float wa = 1.f / (1.f + s);
    float wb = s * wa;
    int s1 = atomicAdd(&counts[e1], 1);
    tok_idx[e1 * TT + s1] = t;
    int s2 = atomicAdd(&counts[e2], 1);
    tok_idx[e2 * TT + s2] = t;
    sel_e[2 * t] = e1; sel_slot[2 * t] = s1; sel_w[2 * t] = wa;
    sel_e[2 * t + 1] = e2; sel_slot[2 * t + 1] = s2; sel_w[2 * t + 1] = wb;
  }
}

__global__ void offsets_kernel(const int* __restrict__ counts, int* __restrict__ offsets) {
  if (threadIdx.x == 0) {
    int r = 0;
    for (int e = 0; e < NE; e++) { offsets[e] = r; r += counts[e]; }
  }
}

// ---------------- gemm1: gated = silu(X w1^T) * (X w3^T), bf16 out ----------------
// Tile 128(M) x 64(F) x {w1,w3}, BK=64.
// WB16: A,B1,B3 all bf16 via GLL (LDS 32KB). else: B fp32 via GLL, cvt on read (LDS 48KB).
// grid: 16384 = x(8) * m(32) * q(64); p = x+8q -> (n = p&63, e = p>>6)
template <bool WB16>
__global__ __launch_bounds__(256) void gemm1_kernel(
    const float* __restrict__ w1f, const float* __restrict__ w3f,
    const unsigned short* __restrict__ w1b, const unsigned short* __restrict__ w3b,
    const unsigned short* __restrict__ hb, const int* __restrict__ tok_idx,
    const int* __restrict__ counts, const int* __restrict__ offsets,
    unsigned short* __restrict__ gated) {
  __shared__ __align__(16) char lds[WB16 ? 32768 : 49152];
  char* Ab = lds;                                  // 128 rows x 128B (bf16)
  char* B1 = lds + 16384;                          // WB16: 64x128B ; else 64x256B
  char* B3 = lds + (WB16 ? 24576 : 32768);

  int bid = blockIdx.x;
  int x = bid & 7;
  int rest = bid >> 3;
  int m = rest & 31;
  int q = rest >> 5;
  int p = x + 8 * q;
  int n = p & 63;
  int e = p >> 6;
  int cnt = counts[e];
  int row0 = m * 128;
  if (row0 >= cnt) return;
  int offe = offsets[e];
  int tid = threadIdx.x;

  long asrc[4];
#pragma unroll
  for (int i = 0; i < 4; i++) {
    int r = i * 32 + (tid >> 3);
    int rr = row0 + r; if (rr >= cnt) rr = cnt - 1;
    int tok = tok_idx[e * TT + rr];
    asrc[i] = (long)tok * DD + (((tid & 7) ^ (r & 7)) * 8);
  }
  int fbase = n * 64;
  long ebase = (long)e * FF * DD;   // expert weight base (ROUND-3 BUG: was missing)
  long bsrc[4];
  if constexpr (WB16) {
#pragma unroll
    for (int i = 0; i < 2; i++) {
      int r = i * 32 + (tid >> 3);
      bsrc[i] = ebase + (long)(fbase + r) * DD + (((tid & 7) ^ (r & 7)) * 8);
    }
  } else {
#pragma unroll
    for (int i = 0; i < 4; i++) {
      int r = i * 16 + (tid >> 4);
      bsrc[i] = ebase + (long)(fbase + r) * DD + (((tid & 15) ^ (r & 15)) * 4);
    }
  }

  f32x4 acc1[4][2], acc3[4][2];
#pragma unroll
  for (int i = 0; i < 4; i++)
#pragma unroll
    for (int j = 0; j < 2; j++) { acc1[i][j] = (f32x4){0,0,0,0}; acc3[i][j] = (f32x4){0,0,0,0}; }

  int wv = tid >> 6;
  int lane = tid & 63;
  int wr = (wv >> 1) * 64;
  int wc = (wv & 1) * 32;
  int lrow = lane & 15;
  int lk4 = lane >> 4;

  for (int k0 = 0; k0 < DD; k0 += 64) {
    if (k0) __syncthreads();
#pragma unroll
    for (int i = 0; i < 4; i++)
      GLL16(hb + asrc[i] + k0, Ab + i * 4096 + tid * 16);
    if constexpr (WB16) {
#pragma unroll
      for (int i = 0; i < 2; i++) {
        GLL16(w1b + bsrc[i] + k0, B1 + i * 4096 + tid * 16);
        GLL16(w3b + bsrc[i] + k0, B3 + i * 4096 + tid * 16);
      }
    } else {
#pragma unroll
      for (int i = 0; i < 4; i++) {
        GLL16(w1f + bsrc[i] + k0, B1 + i * 4096 + tid * 16);
        GLL16(w3f + bsrc[i] + k0, B3 + i * 4096 + tid * 16);
      }
    }
    __syncthreads();
#pragma unroll
    for (int kk = 0; kk < 2; kk++) {
      int kseg = kk * 4 + lk4;          // 8 segs of 16B per 128B row
      int fs = kk * 8 + lk4 * 2;        // 16 segs of 16B per 256B row
      bf16x8 af[4], b1f[2], b3f[2];
#pragma unroll
      for (int i = 0; i < 4; i++) {
        int row = wr + i * 16 + lrow;
        af[i] = *(const bf16x8*)(Ab + row * 128 + ((kseg ^ (row & 7)) * 16));
      }
#pragma unroll
      for (int j = 0; j < 2; j++) {
        int row = wc + j * 16 + lrow;
        if constexpr (WB16) {
          int off = row * 128 + ((kseg ^ (row & 7)) * 16);
          b1f[j] = *(const bf16x8*)(B1 + off);
          b3f[j] = *(const bf16x8*)(B3 + off);
        } else {
          int rx = row & 15;
          float4 a0 = *(const float4*)(B1 + row * 256 + ((fs ^ rx) * 16));
          float4 a1 = *(const float4*)(B1 + row * 256 + (((fs + 1) ^ rx) * 16));
          b1f[j] = cvt8(a0, a1);
          float4 c0 = *(const float4*)(B3 + row * 256 + ((fs ^ rx) * 16));
          float4 c1 = *(const float4*)(B3 + row * 256 + (((fs + 1) ^ rx) * 16));
          b3f[j] = cvt8(c0, c1);
        }
      }
#pragma unroll
      for (int i = 0; i < 4; i++)
#pragma unroll
        for (int j = 0; j < 2; j++) {
          acc1[i][j] = __builtin_amdgcn_mfma_f32_16x16x32_bf16(af[i], b1f[j], acc1[i][j], 0, 0, 0);
          acc3[i][j] = __builtin_amdgcn_mfma_f32_16x16x32_bf16(af[i], b3f[j], acc3[i][j], 0, 0, 0);
        }
    }
  }
  int crow0 = wr + (lane >> 4) * 4;
  int ccol0 = wc + (lane & 15);
#pragma unroll
  for (int i = 0; i < 4; i++)
#pragma unroll
    for (int j = 0; j < 2; j++)
#pragma unroll
      for (int r = 0; r < 4; r++) {
        int trow = crow0 + i * 16 + r;
        if (row0 + trow < cnt) {
          float g = acc1[i][j][r];
          float sg = g / (1.f + __expf(-g));
          float val = sg * acc3[i][j][r];
          gated[(size_t)(offe + row0 + trow) * FF + (fbase + ccol0 + j * 16)] = f2bf(val);
        }
      }
}

// ---------------- gemm2: eout = gated w2^T (fp32 out) ----------------
// Tile 128(M) x 128(D), BK=64, K=FF.
// grid: 4096 = x(8) * m(32) * q(16); p = x+8q -> (n = p&15, e = p>>4)
template <bool WB16>
__global__ __launch_bounds__(256) void gemm2_kernel(
    const float* __restrict__ w2f, const unsigned short* __restrict__ w2b,
    const unsigned short* __restrict__ gated,
    const int* __restrict__ counts, const int* __restrict__ offsets,
    float* __restrict__ eout) {
  __shared__ __align__(16) char lds[WB16 ? 32768 : 49152];
  char* Ab = lds;                    // 128 rows x 128B (bf16)
  char* Bb = lds + 16384;            // WB16: 128x128B ; else 128x256B

  int bid = blockIdx.x;
  int x = bid & 7;
  int rest = bid >> 3;
  int m = rest & 31;
  int q = rest >> 5;
  int p = x + 8 * q;
  int n = p & 15;
  int e = p >> 4;
  int cnt = counts[e];
  int row0 = m * 128;
  if (row0 >= cnt) return;
  int offe = offsets[e];
  int tid = threadIdx.x;

  long asrc[4];
#pragma unroll
  for (int i = 0; i < 4; i++) {
    int r = i * 32 + (tid >> 3);
    int rr = row0 + r; if (rr >= cnt) rr = cnt - 1;
    asrc[i] = (long)(offe + rr) * FF + (((tid & 7) ^ (r & 7)) * 8);
  }
  int dbase = n * 128;
  long ebase = (long)e * DD * FF;   // expert weight base (ROUND-3 BUG: was missing)
  long bsrc[8];
  if constexpr (WB16) {
#pragma unroll
    for (int i = 0; i < 4; i++) {
      int r = i * 32 + (tid >> 3);
      bsrc[i] = ebase + (long)(dbase + r) * FF + (((tid & 7) ^ (r & 7)) * 8);
    }
  } else {
#pragma unroll
    for (int i = 0; i < 8; i++) {
      int r = i * 16 + (tid >> 4);
      bsrc[i] = ebase + (long)(dbase + r) * FF + (((tid & 15) ^ (r & 15)) * 4);
    }
  }

  f32x4 acc[4][4];
#pragma unroll
  for (int i = 0; i < 4; i++)
#pragma unroll
    for (int j = 0; j < 4; j++) acc[i][j] = (f32x4){0,0,0,0};

  int wv = tid >> 6;
  int lane = tid & 63;
  int wr = (wv >> 1) * 64;
  int wc = (wv & 1) * 64;
  int lrow = lane & 15;
  int lk4 = lane >> 4;

  for (int k0 = 0; k0 < FF; k0 += 64) {
    if (k0) __syncthreads();
#pragma unroll
    for (int i = 0; i < 4; i++)
      GLL16(gated + asrc[i] + k0, Ab + i * 4096 + tid * 16);
    if constexpr (WB16) {
#pragma unroll
      for (int i = 0; i < 4; i++)
        GLL16(w2b + bsrc[i] + k0, Bb + i * 4096 + tid * 16);
    } else {
#pragma unroll
      for (int i = 0; i < 8; i++)
        GLL16(w2f + bsrc[i] + k0, Bb + i * 4096 + tid * 16);
    }
    __syncthreads();
#pragma unroll
    for (int kk = 0; kk < 2; kk++) {
      int kseg = kk * 4 + lk4;
      int fs = kk * 8 + lk4 * 2;
      bf16x8 af[4], bf[4];
#pragma unroll
      for (int i = 0; i < 4; i++) {
        int row = wr + i * 16 + lrow;
        af[i] = *(const bf16x8*)(Ab + row * 128 + ((kseg ^ (row & 7)) * 16));
      }
#pragma unroll
      for (int j = 0; j < 4; j++) {
        int row = wc + j * 16 + lrow;
        if constexpr (WB16) {
          bf[j] = *(const bf16x8*)(Bb + row * 128 + ((kseg ^ (row & 7)) * 16));
        } else {
          int rx = row & 15;
          float4 a0 = *(const float4*)(Bb + row * 256 + ((fs ^ rx) * 16));
          float4 a1 = *(const float4*)(Bb + row * 256 + (((fs + 1) ^ rx) * 16));
          bf[j] = cvt8(a0, a1);
        }
      }
#pragma unroll
      for (int i = 0; i < 4; i++)
#pragma unroll
        for (int j = 0; j < 4; j++)
          acc[i][j] = __builtin_amdgcn_mfma_f32_16x16x32_bf16(af[i], bf[j], acc[i][j], 0, 0, 0);
    }
  }
  int crow0 = wr + (lane >> 4) * 4;
  int ccol0 = wc + (lane & 15);
#pragma unroll
  for (int i = 0; i < 4; i++)
#pragma unroll
    for (int j = 0; j < 4; j++)
#pragma unroll
      for (int r = 0; r < 4; r++) {
        int trow = crow0 + i * 16 + r;
        if (row0 + trow < cnt)
          eout[(size_t)(offe + row0 + trow) * DD + (dbase + ccol0 + j * 16)] = acc[i][j][r];
      }
}

// ---------------- gather: final = sum_k w_k * eout[slot_k] ----------------
__global__ void gather_kernel(const float* __restrict__ eout, const int* __restrict__ offsets,
                              const int* __restrict__ sel_e, const int* __restrict__ sel_slot,
                              const float* __restrict__ sel_w, float* __restrict__ out) {
  int idx = blockIdx.x * 256 + threadIdx.x;
  int t = idx >> 9;
  int c = idx & 511;
  int ea = sel_e[2 * t], eb = sel_e[2 * t + 1];
  int sa = offsets[ea] + sel_slot[2 * t];
  int sb = offsets[eb] + sel_slot[2 * t + 1];
  float wa = sel_w[2 * t], wb = sel_w[2 * t + 1];
  float4 va = ((const float4*)(eout + (size_t)sa * DD))[c];
  float4 vb = ((const float4*)(eout + (size_t)sb * DD))[c];
  float4 o;
  o.x = wa * va.x + wb * vb.x;
  o.y = wa * va.y + wb * vb.y;
  o.z = wa * va.z + wb * vb.z;
  o.w = wa * va.w + wb * vb.w;
  ((float4*)(out + (size_t)t * DD))[c] = o;
}

extern "C" void kernel_launch(void* const* d_in, const int* in_sizes, int n_in,
                              void* d_out, int out_size, void* d_ws, size_t ws_size,
                              hipStream_t stream) {
  const float* h  = (const float*)d_in[0];
  const float* gw = (const float*)d_in[1];
  const float* w1 = (const float*)d_in[2];
  const float* w2 = (const float*)d_in[3];
  const float* w3 = (const float*)d_in[4];
  float* out = (float*)d_out;
  float* logits = out + (size_t)TT * DD;

  char* wp = (char*)d_ws;
  int* counts = (int*)wp; wp += 256;
  int* offsets = (int*)wp; wp += 256;
  int* tok_idx = (int*)wp; wp += (size_t)NE * TT * 4;
  int* sel_e = (int*)wp; wp += (size_t)TT * 2 * 4;
  int* sel_slot = (int*)wp; wp += (size_t)TT * 2 * 4;
  float* sel_w = (float*)wp; wp += (size_t)TT * 2 * 4;
  unsigned short* hb = (unsigned short*)wp; wp += (size_t)TT * DD * 2;
  unsigned short* gated = (unsigned short*)wp; wp += (size_t)TT * TKK * FF * 2;
  float* eout = (float*)wp; wp += (size_t)TT * TKK * DD * 4;
  if ((size_t)(wp - (char*)d_ws) > ws_size) return;  // base scratch must fit

  // optional bf16 weight mirrors
  long nw = (long)NE * FF * DD;                       // 67.1M elems per tensor
  unsigned short* w1b = (unsigned short*)wp; wp += (size_t)nw * 2;
  unsigned short* w3b = (unsigned short*)wp; wp += (size_t)nw * 2;
  unsigned short* w2b = (unsigned short*)wp; wp += (size_t)nw * 2;
  bool wb16 = ((size_t)(wp - (char*)d_ws) <= ws_size);

  hipMemsetAsync(counts, 0, 32, stream);
  router_kernel<<<TT, 64, 0, stream>>>(h, gw, logits, hb, counts, tok_idx, sel_e, sel_slot, sel_w);
  offsets_kernel<<<1, 64, 0, stream>>>(counts, offsets);
  if (wb16) {
    convert_kernel<<<4096, 256, 0, stream>>>(w1, w1b, nw);
    convert_kernel<<<4096, 256, 0, stream>>>(w3, w3b, nw);
    convert_kernel<<<4096, 256, 0, stream>>>(w2, w2b, nw);
    gemm1_kernel<true><<<8 * 32 * 64, 256, 0, stream>>>(w1, w3, w1b, w3b, hb, tok_idx, counts, offsets, gated);
    gemm2_kernel<true><<<8 * 32 * 16, 256, 0, stream>>>(w2, w2b, gated, counts, offsets, eout);
  } else {
    gemm1_kernel<false><<<8 * 32 * 64, 256, 0, stream>>>(w1, w3, nullptr, nullptr, hb, tok_idx, counts, offsets, gated);
    gemm2_kernel<false><<<8 * 32 * 16, 256, 0, stream>>>(w2, nullptr, gated, counts, offsets, eout);
  }
  gather_kernel<<<(TT * DD / 4) / 256, 256, 0, stream>>>(eout, offsets, sel_e, sel_slot, sel_w, out);
}

// Round 5
// 850.018 us; speedup vs baseline: 1.8452x; 1.0124x over previous
//
#include <hip/hip_runtime.h>
#include <hip/hip_bf16.h>
#include <stdint.h>

#define NE 8
#define TKK 2
#define DD 2048
#define FF 4096
#define TT 4096   // tokens = 2*2048
#define CONV13 2048   // convert blocks fused with router (w1,w3)
#define CONV2  1024   // convert blocks fused with gemm1 (w2)

typedef __attribute__((ext_vector_type(8))) short bf16x8;
typedef __attribute__((ext_vector_type(4))) float f32x4;

__device__ inline unsigned short f2bf(float f) {
  union { float f; unsigned u; } x; x.f = f;
  unsigned r = x.u + 0x7fffu + ((x.u >> 16) & 1u);
  return (unsigned short)(r >> 16);
}

__device__ inline bf16x8 cvt8(float4 a, float4 b) {
  union { unsigned short h[8]; bf16x8 v; } x;
  x.h[0] = f2bf(a.x); x.h[1] = f2bf(a.y); x.h[2] = f2bf(a.z); x.h[3] = f2bf(a.w);
  x.h[4] = f2bf(b.x); x.h[5] = f2bf(b.y); x.h[6] = f2bf(b.z); x.h[7] = f2bf(b.w);
  return x.v;
}

__device__ __forceinline__ void conv8(const float* __restrict__ src,
                                      unsigned short* __restrict__ dst, long i) {
  float4 a = *(const float4*)(src + i);
  float4 b = *(const float4*)(src + i + 4);
  union { unsigned short h[8]; uint4 v; } o;
  o.h[0] = f2bf(a.x); o.h[1] = f2bf(a.y); o.h[2] = f2bf(a.z); o.h[3] = f2bf(a.w);
  o.h[4] = f2bf(b.x); o.h[5] = f2bf(b.y); o.h[6] = f2bf(b.z); o.h[7] = f2bf(b.w);
  *(uint4*)(dst + i) = o.v;
}

#define GLL16(g, l) __builtin_amdgcn_global_load_lds( \
    (__attribute__((address_space(1))) void*)(void*)(g), \
    (__attribute__((address_space(3))) void*)(l), 16, 0, 0)

// ---------------- router body (one wave = one token) ----------------
__device__ __forceinline__ void router_one(
    int t, int lane, const float* __restrict__ h, const float* __restrict__ gw,
    float* __restrict__ logits, unsigned short* __restrict__ hb,
    int* __restrict__ counts, int* __restrict__ tok_idx,
    int* __restrict__ sel_e, int* __restrict__ sel_slot, float* __restrict__ sel_w) {
  const float4* hr = (const float4*)(h + (size_t)t * DD);
  float4 hv[8];
  float acc[NE];
#pragma unroll
  for (int e = 0; e < NE; e++) acc[e] = 0.f;
#pragma unroll
  for (int j = 0; j < 8; j++) hv[j] = hr[j * 64 + lane];
  ushort4* hbr = (ushort4*)(hb + (size_t)t * DD);
#pragma unroll
  for (int j = 0; j < 8; j++) {
    ushort4 o;
    o.x = f2bf(hv[j].x); o.y = f2bf(hv[j].y); o.z = f2bf(hv[j].z); o.w = f2bf(hv[j].w);
    hbr[j * 64 + lane] = o;
  }
#pragma unroll
  for (int e = 0; e < NE; e++) {
    const float4* g = (const float4*)(gw + (size_t)e * DD);
    float a = 0.f;
#pragma unroll
    for (int j = 0; j < 8; j++) {
      float4 gv = g[j * 64 + lane];
      a += hv[j].x * gv.x + hv[j].y * gv.y + hv[j].z * gv.z + hv[j].w * gv.w;
    }
    acc[e] = a;
  }
#pragma unroll
  for (int e = 0; e < NE; e++) {
    float v = acc[e];
#pragma unroll
    for (int o = 32; o > 0; o >>= 1) v += __shfl_xor(v, o, 64);
    acc[e] = v;
  }
  if (lane == 0) {
#pragma unroll
    for (int e = 0; e < NE; e++) logits[(size_t)t * NE + e] = acc[e];
    int e1 = 0; float m1 = acc[0];
#pragma unroll
    for (int e = 1; e < NE; e++) if (acc[e] > m1) { m1 = acc[e]; e1 = e; }
    int e2 = -1; float m2 = -3.4e38f;
#pragma unroll
    for (int e = 0; e < NE; e++) if (e != e1 && acc[e] > m2) { m2 = acc[e]; e2 = e; }
    float s = expf(m2 - m1);
    float wa = 1.f / (1.f + s);
    float wb = s * wa;
    int s1 = atomicAdd(&counts[e1], 1);
    tok_idx[e1 * TT + s1] = t;
    int s2 = atomicAdd(&counts[e2], 1);
    tok_idx[e2 * TT + s2] = t;
    sel_e[2 * t] = e1; sel_slot[2 * t] = s1; sel_w[2 * t] = wa;
    sel_e[2 * t + 1] = e2; sel_slot[2 * t + 1] = s2; sel_w[2 * t + 1] = wb;
  }
}

// fallback standalone router (non-wb16 path)
__global__ void router_kernel(const float* __restrict__ h, const float* __restrict__ gw,
                              float* __restrict__ logits, unsigned short* __restrict__ hb,
                              int* __restrict__ counts, int* __restrict__ tok_idx,
                              int* __restrict__ sel_e, int* __restrict__ sel_slot,
                              float* __restrict__ sel_w) {
  router_one(blockIdx.x, threadIdx.x, h, gw, logits, hb, counts, tok_idx, sel_e, sel_slot, sel_w);
}

// ---------------- prep: w1/w3 convert + router, fused in one dispatch ----------------
// grid = CONV13 + TT/4; convert blocks stream fp32->bf16 (HBM-bound) while router
// blocks (compute-light) run concurrently.
__global__ __launch_bounds__(256) void prep_kernel(
    const float* __restrict__ h, const float* __restrict__ gw,
    float* __restrict__ logits, unsigned short* __restrict__ hb,
    int* __restrict__ counts, int* __restrict__ tok_idx,
    int* __restrict__ sel_e, int* __restrict__ sel_slot, float* __restrict__ sel_w,
    const float* __restrict__ w1, unsigned short* __restrict__ w1b,
    const float* __restrict__ w3, unsigned short* __restrict__ w3b) {
  if (blockIdx.x < CONV13) {
    long nw = (long)NE * FF * DD;
    long i = ((long)blockIdx.x * 256 + threadIdx.x) * 8;
    long stride = (long)CONV13 * 256 * 8;
    for (; i < 2 * nw; i += stride) {
      if (i < nw) conv8(w1, w1b, i);
      else        conv8(w3, w3b, i - nw);
    }
    return;
  }
  int b = blockIdx.x - CONV13;
  router_one(b * 4 + (threadIdx.x >> 6), threadIdx.x & 63,
             h, gw, logits, hb, counts, tok_idx, sel_e, sel_slot, sel_w);
}

__global__ void offsets_kernel(const int* __restrict__ counts, int* __restrict__ offsets) {
  if (threadIdx.x == 0) {
    int r = 0;
    for (int e = 0; e < NE; e++) { offsets[e] = r; r += counts[e]; }
  }
}

// ---------------- gemm1 (+ fused w2 convert): gated = silu(X w1^T) * (X w3^T) ----------------
// Tile 128(M) x 64(F), BK=64, all-bf16 via GLL. First CONV2 blocks convert w2.
// gemm grid part: 16384 = x(8) * m(32) * q(64); p = x+8q -> (n = p&63, e = p>>6)
__global__ __launch_bounds__(256) void gemm1c_kernel(
    const unsigned short* __restrict__ w1b, const unsigned short* __restrict__ w3b,
    const unsigned short* __restrict__ hb, const int* __restrict__ tok_idx,
    const int* __restrict__ counts, const int* __restrict__ offsets,
    unsigned short* __restrict__ gated,
    const float* __restrict__ w2f, unsigned short* __restrict__ w2b) {
  __shared__ __align__(16) char lds[32768];
  char* Ab = lds;              // 128 rows x 128B (bf16)
  char* B1 = lds + 16384;      // 64 rows x 128B
  char* B3 = lds + 24576;      // 64 rows x 128B

  if (blockIdx.x < CONV2) {    // fused w2 fp32->bf16 convert (hides under gemm compute)
    long nw = (long)NE * FF * DD;
    long i = ((long)blockIdx.x * 256 + threadIdx.x) * 8;
    long stride = (long)CONV2 * 256 * 8;
    for (; i < nw; i += stride) conv8(w2f, w2b, i);
    return;
  }

  int bid = blockIdx.x - CONV2;
  int x = bid & 7;
  int rest = bid >> 3;
  int m = rest & 31;
  int q = rest >> 5;
  int p = x + 8 * q;
  int n = p & 63;
  int e = p >> 6;
  int cnt = counts[e];
  int row0 = m * 128;
  if (row0 >= cnt) return;
  int offe = offsets[e];
  int tid = threadIdx.x;

  long asrc[4];
#pragma unroll
  for (int i = 0; i < 4; i++) {
    int r = i * 32 + (tid >> 3);
    int rr = row0 + r; if (rr >= cnt) rr = cnt - 1;
    int tok = tok_idx[e * TT + rr];
    asrc[i] = (long)tok * DD + (((tid & 7) ^ (r & 7)) * 8);
  }
  int fbase = n * 64;
  long ebase = (long)e * FF * DD;
  long bsrc[2];
#pragma unroll
  for (int i = 0; i < 2; i++) {
    int r = i * 32 + (tid >> 3);
    bsrc[i] = ebase + (long)(fbase + r) * DD + (((tid & 7) ^ (r & 7)) * 8);
  }

  f32x4 acc1[4][2], acc3[4][2];
#pragma unroll
  for (int i = 0; i < 4; i++)
#pragma unroll
    for (int j = 0; j < 2; j++) { acc1[i][j] = (f32x4){0,0,0,0}; acc3[i][j] = (f32x4){0,0,0,0}; }

  int wv = tid >> 6;
  int lane = tid & 63;
  int wr = (wv >> 1) * 64;
  int wc = (wv & 1) * 32;
  int lrow = lane & 15;
  int lk4 = lane >> 4;

  for (int k0 = 0; k0 < DD; k0 += 64) {
    if (k0) __syncthreads();
#pragma unroll
    for (int i = 0; i < 4; i++)
      GLL16(hb + asrc[i] + k0, Ab + i * 4096 + tid * 16);
#pragma unroll
    for (int i = 0; i < 2; i++) {
      GLL16(w1b + bsrc[i] + k0, B1 + i * 4096 + tid * 16);
      GLL16(w3b + bsrc[i] + k0, B3 + i * 4096 + tid * 16);
    }
    __syncthreads();
#pragma unroll
    for (int kk = 0; kk < 2; kk++) {
      int kseg = kk * 4 + lk4;
      bf16x8 af[4], b1f[2], b3f[2];
#pragma unroll
      for (int i = 0; i < 4; i++) {
        int row = wr + i * 16 + lrow;
        af[i] = *(const bf16x8*)(Ab + row * 128 + ((kseg ^ (row & 7)) * 16));
      }
#pragma unroll
      for (int j = 0; j < 2; j++) {
        int row = wc + j * 16 + lrow;
        int off = row * 128 + ((kseg ^ (row & 7)) * 16);
        b1f[j] = *(const bf16x8*)(B1 + off);
        b3f[j] = *(const bf16x8*)(B3 + off);
      }
#pragma unroll
      for (int i = 0; i < 4; i++)
#pragma unroll
        for (int j = 0; j < 2; j++) {
          acc1[i][j] = __builtin_amdgcn_mfma_f32_16x16x32_bf16(af[i], b1f[j], acc1[i][j], 0, 0, 0);
          acc3[i][j] = __builtin_amdgcn_mfma_f32_16x16x32_bf16(af[i], b3f[j], acc3[i][j], 0, 0, 0);
        }
    }
  }
  int crow0 = wr + (lane >> 4) * 4;
  int ccol0 = wc + (lane & 15);
#pragma unroll
  for (int i = 0; i < 4; i++)
#pragma unroll
    for (int j = 0; j < 2; j++)
#pragma unroll
      for (int r = 0; r < 4; r++) {
        int trow = crow0 + i * 16 + r;
        if (row0 + trow < cnt) {
          float g = acc1[i][j][r];
          float sg = g / (1.f + __expf(-g));
          float val = sg * acc3[i][j][r];
          gated[(size_t)(offe + row0 + trow) * FF + (fbase + ccol0 + j * 16)] = f2bf(val);
        }
      }
}

// ---------------- fallback gemm1 (fp32 weights direct, no ws mirrors) ----------------
__global__ __launch_bounds__(256) void gemm1_kernel_fb(
    const float* __restrict__ w1f, const float* __restrict__ w3f,
    const unsigned short* __restrict__ hb, const int* __restrict__ tok_idx,
    const int* __restrict__ counts, const int* __restrict__ offsets,
    unsigned short* __restrict__ gated) {
  __shared__ __align__(16) char lds[49152];
  char* Ab = lds;
  char* B1 = lds + 16384;
  char* B3 = lds + 32768;

  int bid = blockIdx.x;
  int x = bid & 7;
  int rest = bid >> 3;
  int m = rest & 31;
  int q = rest >> 5;
  int p = x + 8 * q;
  int n = p & 63;
  int e = p >> 6;
  int cnt = counts[e];
  int row0 = m * 128;
  if (row0 >= cnt) return;
  int offe = offsets[e];
  int tid = threadIdx.x;

  long asrc[4];
#pragma unroll
  for (int i = 0; i < 4; i++) {
    int r = i * 32 + (tid >> 3);
    int rr = row0 + r; if (rr >= cnt) rr = cnt - 1;
    int tok = tok_idx[e * TT + rr];
    asrc[i] = (long)tok * DD + (((tid & 7) ^ (r & 7)) * 8);
  }
  int fbase = n * 64;
  long ebase = (long)e * FF * DD;
  long bsrc[4];
#pragma unroll
  for (int i = 0; i < 4; i++) {
    int r = i * 16 + (tid >> 4);
    bsrc[i] = ebase + (long)(fbase + r) * DD + (((tid & 15) ^ (r & 15)) * 4);
  }

  f32x4 acc1[4][2], acc3[4][2];
#pragma unroll
  for (int i = 0; i < 4; i++)
#pragma unroll
    for (int j = 0; j < 2; j++) { acc1[i][j] = (f32x4){0,0,0,0}; acc3[i][j] = (f32x4){0,0,0,0}; }

  int wv = tid >> 6;
  int lane = tid & 63;
  int wr = (wv >> 1) * 64;
  int wc = (wv & 1) * 32;
  int lrow = lane & 15;
  int lk4 = lane >> 4;

  for (int k0 = 0; k0 < DD; k0 += 64) {
    if (k0) __syncthreads();
#pragma unroll
    for (int i = 0; i < 4; i++)
      GLL16(hb + asrc[i] + k0, Ab + i * 4096 + tid * 16);
#pragma unroll
    for (int i = 0; i < 4; i++) {
      GLL16(w1f + bsrc[i] + k0, B1 + i * 4096 + tid * 16);
      GLL16(w3f + bsrc[i] + k0, B3 + i * 4096 + tid * 16);
    }
    __syncthreads();
#pragma unroll
    for (int kk = 0; kk < 2; kk++) {
      int kseg = kk * 4 + lk4;
      int fs = kk * 8 + lk4 * 2;
      bf16x8 af[4], b1f[2], b3f[2];
#pragma unroll
      for (int i = 0; i < 4; i++) {
        int row = wr + i * 16 + lrow;
        af[i] = *(const bf16x8*)(Ab + row * 128 + ((kseg ^ (row & 7)) * 16));
      }
#pragma unroll
      for (int j = 0; j < 2; j++) {
        int row = wc + j * 16 + lrow;
        int rx = row & 15;
        float4 a0 = *(const float4*)(B1 + row * 256 + ((fs ^ rx) * 16));
        float4 a1 = *(const float4*)(B1 + row * 256 + (((fs + 1) ^ rx) * 16));
        b1f[j] = cvt8(a0, a1);
        float4 c0 = *(const float4*)(B3 + row * 256 + ((fs ^ rx) * 16));
        float4 c1 = *(const float4*)(B3 + row * 256 + (((fs + 1) ^ rx) * 16));
        b3f[j] = cvt8(c0, c1);
      }
#pragma unroll
      for (int i = 0; i < 4; i++)
#pragma unroll
        for (int j = 0; j < 2; j++) {
          acc1[i][j] = __builtin_amdgcn_mfma_f32_16x16x32_bf16(af[i], b1f[j], acc1[i][j], 0, 0, 0);
          acc3[i][j] = __builtin_amdgcn_mfma_f32_16x16x32_bf16(af[i], b3f[j], acc3[i][j], 0, 0, 0);
        }
    }
  }
  int crow0 = wr + (lane >> 4) * 4;
  int ccol0 = wc + (lane & 15);
#pragma unroll
  for (int i = 0; i < 4; i++)
#pragma unroll
    for (int j = 0; j < 2; j++)
#pragma unroll
      for (int r = 0; r < 4; r++) {
        int trow = crow0 + i * 16 + r;
        if (row0 + trow < cnt) {
          float g = acc1[i][j][r];
          float sg = g / (1.f + __expf(-g));
          float val = sg * acc3[i][j][r];
          gated[(size_t)(offe + row0 + trow) * FF + (fbase + ccol0 + j * 16)] = f2bf(val);
        }
      }
}

// ---------------- gemm2: eout = gated w2^T (fp32 out) ----------------
// Tile 128(M) x 128(D), BK=64, K=FF.
// grid: 4096 = x(8) * m(32) * q(16); p = x+8q -> (n = p&15, e = p>>4)
template <bool WB16>
__global__ __launch_bounds__(256) void gemm2_kernel(
    const float* __restrict__ w2f, const unsigned short* __restrict__ w2b,
    const unsigned short* __restrict__ gated,
    const int* __restrict__ counts, const int* __restrict__ offsets,
    float* __restrict__ eout) {
  __shared__ __align__(16) char lds[WB16 ? 32768 : 49152];
  char* Ab = lds;
  char* Bb = lds + 16384;

  int bid = blockIdx.x;
  int x = bid & 7;
  int rest = bid >> 3;
  int m = rest & 31;
  int q = rest >> 5;
  int p = x + 8 * q;
  int n = p & 15;
  int e = p >> 4;
  int cnt = counts[e];
  int row0 = m * 128;
  if (row0 >= cnt) return;
  int offe = offsets[e];
  int tid = threadIdx.x;

  long asrc[4];
#pragma unroll
  for (int i = 0; i < 4; i++) {
    int r = i * 32 + (tid >> 3);
    int rr = row0 + r; if (rr >= cnt) rr = cnt - 1;
    asrc[i] = (long)(offe + rr) * FF + (((tid & 7) ^ (r & 7)) * 8);
  }
  int dbase = n * 128;
  long ebase = (long)e * DD * FF;
  long bsrc[8];
  if constexpr (WB16) {
#pragma unroll
    for (int i = 0; i < 4; i++) {
      int r = i * 32 + (tid >> 3);
      bsrc[i] = ebase + (long)(dbase + r) * FF + (((tid & 7) ^ (r & 7)) * 8);
    }
  } else {
#pragma unroll
    for (int i = 0; i < 8; i++) {
      int r = i * 16 + (tid >> 4);
      bsrc[i] = ebase + (long)(dbase + r) * FF + (((tid & 15) ^ (r & 15)) * 4);
    }
  }

  f32x4 acc[4][4];
#pragma unroll
  for (int i = 0; i < 4; i++)
#pragma unroll
    for (int j = 0; j < 4; j++) acc[i][j] = (f32x4){0,0,0,0};

  int wv = tid >> 6;
  int lane = tid & 63;
  int wr = (wv >> 1) * 64;
  int wc = (wv & 1) * 64;
  int lrow = lane & 15;
  int lk4 = lane >> 4;

  for (int k0 = 0; k0 < FF; k0 += 64) {
    if (k0) __syncthreads();
#pragma unroll
    for (int i = 0; i < 4; i++)
      GLL16(gated + asrc[i] + k0, Ab + i * 4096 + tid * 16);
    if constexpr (WB16) {
#pragma unroll
      for (int i = 0; i < 4; i++)
        GLL16(w2b + bsrc[i] + k0, Bb + i * 4096 + tid * 16);
    } else {
#pragma unroll
      for (int i = 0; i < 8; i++)
        GLL16(w2f + bsrc[i] + k0, Bb + i * 4096 + tid * 16);
    }
    __syncthreads();
#pragma unroll
    for (int kk = 0; kk < 2; kk++) {
      int kseg = kk * 4 + lk4;
      int fs = kk * 8 + lk4 * 2;
      bf16x8 af[4], bf[4];
#pragma unroll
      for (int i = 0; i < 4; i++) {
        int row = wr + i * 16 + lrow;
        af[i] = *(const bf16x8*)(Ab + row * 128 + ((kseg ^ (row & 7)) * 16));
      }
#pragma unroll
      for (int j = 0; j < 4; j++) {
        int row = wc + j * 16 + lrow;
        if constexpr (WB16) {
          bf[j] = *(const bf16x8*)(Bb + row * 128 + ((kseg ^ (row & 7)) * 16));
        } else {
          int rx = row & 15;
          float4 a0 = *(const float4*)(Bb + row * 256 + ((fs ^ rx) * 16));
          float4 a1 = *(const float4*)(Bb + row * 256 + (((fs + 1) ^ rx) * 16));
          bf[j] = cvt8(a0, a1);
        }
      }
#pragma unroll
      for (int i = 0; i < 4; i++)
#pragma unroll
        for (int j = 0; j < 4; j++)
          acc[i][j] = __builtin_amdgcn_mfma_f32_16x16x32_bf16(af[i], bf[j], acc[i][j], 0, 0, 0);
    }
  }
  int crow0 = wr + (lane >> 4) * 4;
  int ccol0 = wc + (lane & 15);
#pragma unroll
  for (int i = 0; i < 4; i++)
#pragma unroll
    for (int j = 0; j < 4; j++)
#pragma unroll
      for (int r = 0; r < 4; r++) {
        int trow = crow0 + i * 16 + r;
        if (row0 + trow < cnt)
          eout[(size_t)(offe + row0 + trow) * DD + (dbase + ccol0 + j * 16)] = acc[i][j][r];
      }
}

// ---------------- gather: final = sum_k w_k * eout[slot_k] ----------------
__global__ void gather_kernel(const float* __restrict__ eout, const int* __restrict__ offsets,
                              const int* __restrict__ sel_e, const int* __restrict__ sel_slot,
                              const float* __restrict__ sel_w, float* __restrict__ out) {
  int idx = blockIdx.x * 256 + threadIdx.x;
  int t = idx >> 9;
  int c = idx & 511;
  int ea = sel_e[2 * t], eb = sel_e[2 * t + 1];
  int sa = offsets[ea] + sel_slot[2 * t];
  int sb = offsets[eb] + sel_slot[2 * t + 1];
  float wa = sel_w[2 * t], wb = sel_w[2 * t + 1];
  float4 va = ((const float4*)(eout + (size_t)sa * DD))[c];
  float4 vb = ((const float4*)(eout + (size_t)sb * DD))[c];
  float4 o;
  o.x = wa * va.x + wb * vb.x;
  o.y = wa * va.y + wb * vb.y;
  o.z = wa * va.z + wb * vb.z;
  o.w = wa * va.w + wb * vb.w;
  ((float4*)(out + (size_t)t * DD))[c] = o;
}

extern "C" void kernel_launch(void* const* d_in, const int* in_sizes, int n_in,
                              void* d_out, int out_size, void* d_ws, size_t ws_size,
                              hipStream_t stream) {
  const float* h  = (const float*)d_in[0];
  const float* gw = (const float*)d_in[1];
  const float* w1 = (const float*)d_in[2];
  const float* w2 = (const float*)d_in[3];
  const float* w3 = (const float*)d_in[4];
  float* out = (float*)d_out;
  float* logits = out + (size_t)TT * DD;

  char* wp = (char*)d_ws;
  int* counts = (int*)wp; wp += 256;
  int* offsets = (int*)wp; wp += 256;
  int* tok_idx = (int*)wp; wp += (size_t)NE * TT * 4;
  int* sel_e = (int*)wp; wp += (size_t)TT * 2 * 4;
  int* sel_slot = (int*)wp; wp += (size_t)TT * 2 * 4;
  float* sel_w = (float*)wp; wp += (size_t)TT * 2 * 4;
  unsigned short* hb = (unsigned short*)wp; wp += (size_t)TT * DD * 2;
  unsigned short* gated = (unsigned short*)wp; wp += (size_t)TT * TKK * FF * 2;
  float* eout = (float*)wp; wp += (size_t)TT * TKK * DD * 4;
  if ((size_t)(wp - (char*)d_ws) > ws_size) return;  // base scratch must fit

  long nw = (long)NE * FF * DD;
  unsigned short* w1b = (unsigned short*)wp; wp += (size_t)nw * 2;
  unsigned short* w3b = (unsigned short*)wp; wp += (size_t)nw * 2;
  unsigned short* w2b = (unsigned short*)wp; wp += (size_t)nw * 2;
  bool wb16 = ((size_t)(wp - (char*)d_ws) <= ws_size);

  hipMemsetAsync(counts, 0, 32, stream);
  if (wb16) {
    prep_kernel<<<CONV13 + TT / 4, 256, 0, stream>>>(
        h, gw, logits, hb, counts, tok_idx, sel_e, sel_slot, sel_w, w1, w1b, w3, w3b);
    offsets_kernel<<<1, 64, 0, stream>>>(counts, offsets);
    gemm1c_kernel<<<CONV2 + 8 * 32 * 64, 256, 0, stream>>>(
        w1b, w3b, hb, tok_idx, counts, offsets, gated, w2, w2b);
    gemm2_kernel<true><<<8 * 32 * 16, 256, 0, stream>>>(w2, w2b, gated, counts, offsets, eout);
  } else {
    router_kernel<<<TT, 64, 0, stream>>>(h, gw, logits, hb, counts, tok_idx, sel_e, sel_slot, sel_w);
    offsets_kernel<<<1, 64, 0, stream>>>(counts, offsets);
    gemm1_kernel_fb<<<8 * 32 * 64, 256, 0, stream>>>(w1, w3, hb, tok_idx, counts, offsets, gated);
    gemm2_kernel<false><<<8 * 32 * 16, 256, 0, stream>>>(w2, nullptr, gated, counts, offsets, eout);
  }
  gather_kernel<<<(TT * DD / 4) / 256, 256, 0, stream>>>(eout, offsets, sel_e, sel_slot, sel_w, out);
}